// Round 16
// baseline (319.622 us; speedup 1.0000x reference)
//
#include <hip/hip_runtime.h>
#include <hip/hip_bf16.h>

// 6 layers of relu(spmm(graph, x@W+b)), B=256, NN=255 nodes.
// R31 = R30 resubmitted verbatim (previous bench died on container
// acquisition, no kernel signal).  R30 = R29 with fused_layer retiled
// 128-f -> 64-f (8 waves, 512 thr kept): LDS 64KB -> 45KB (As 3x4KB +
// Bs 2x16KB; Ys 32KB overlay) => 3 blocks/CU = 24 waves/CU (+50%).
// Occupancy is the one proven lever (R24: 8->16 waves/CU gave -33%).
// acc[2][4] keeps VGPR <= 64 (the 24-wave budget).  As staged by waves
// 0-3 only (1 DMA, 16 rows each); Bs by all waves (2 DMAs, own 32 rows);
// per-wave counted vmcnt: 3 (w<4) / 2 (w>=4) -- each wave's counter
// tracks its own loads; the k-step barrier publishes the stagers'
// completed As to all waves.  Swizzle key (frow>>1)&3 and all epilogue
// algebra unchanged (j<4, YCH=2048).  Grids nft 5/2/5/7.

#define NN 255
#define YCH 2048           // ushorts per Y chunk: 64 rows * 32

typedef __attribute__((ext_vector_type(8))) short short8;
typedef __attribute__((ext_vector_type(4))) float floatx4;

__device__ __forceinline__ float bf2f(ushort u) {
    union { uint u; float f; } c; c.u = ((uint)u) << 16; return c.f;
}
// native scalar cast (fptrunc, RNE) -> backend emits v_cvt_pk_bf16_f32
__device__ __forceinline__ ushort f2bf(float f) {
    __bf16 h = (__bf16)f;
    ushort u; __builtin_memcpy(&u, &h, 2); return u;
}
__device__ __forceinline__ short8 u4_frag(uint4 v) {
    union { uint4 u; short8 s; } c; c.u = v; return c.s;
}
// global -> LDS DMA, 16B per lane (dest = lds + lane*16, src per-lane)
__device__ __forceinline__ void gl_lds16(const ushort* g, ushort* l) {
    __builtin_amdgcn_global_load_lds(
        (const __attribute__((address_space(1))) void*)g,
        (__attribute__((address_space(3))) void*)l, 16, 0, 0);
}

// ---------------- graph preprocessing ----------------
__global__ void zero_k(int* p, int n) {
    int i = blockIdx.x * blockDim.x + threadIdx.x;
    if (i < n) p[i] = 0;
}

// per-edge: dense-S scatter + rowsum (f32 atomics)
__global__ void edge_k(const int* __restrict__ r0, const int* __restrict__ c0, const float* __restrict__ v0,
                       const int* __restrict__ r1, const int* __restrict__ c1, const float* __restrict__ v1,
                       const int* __restrict__ r2, const int* __restrict__ c2, const float* __restrict__ v2,
                       const int* __restrict__ r3, const int* __restrict__ c3, const float* __restrict__ v3,
                       float* Sd, float* rs, int nnz) {
    int gi = blockIdx.y;
    int e = blockIdx.x * blockDim.x + threadIdx.x;
    if (e >= nnz) return;
    const int* rr = gi == 0 ? r0 : gi == 1 ? r1 : gi == 2 ? r2 : r3;
    const int* cc = gi == 0 ? c0 : gi == 1 ? c1 : gi == 2 ? c2 : c3;
    const float* vv = gi == 0 ? v0 : gi == 1 ? v1 : gi == 2 ? v2 : v3;
    int r = rr[e], c = cc[e];
    float v = vv[e];
    atomicAdd(&Sd[gi * 65536 + r * 256 + c], v);
    atomicAdd(&rs[gi * 256 + r], v);
}

// merged converts: Sd->Sb (bf16) then 4 weight transposes (ladder on idx)
__device__ __forceinline__ void wpiece(const float* __restrict__ W, ushort* __restrict__ Wt,
                                       int K, int N, int Kpad, int idx) {
    int n = idx / Kpad, k = idx - n * Kpad;
    float v = (n < N && k < K) ? W[(size_t)k * N + n] : 0.f;
    Wt[idx] = f2bf(v);
}

__global__ void conv_k(const float* __restrict__ Sd, ushort* __restrict__ Sb,
                       const float* __restrict__ W1, ushort* __restrict__ Wt1,
                       const float* __restrict__ W2, ushort* __restrict__ Wt2,
                       const float* __restrict__ W3, ushort* __restrict__ Wt3,
                       const float* __restrict__ W4, ushort* __restrict__ Wt4) {
    int idx = blockIdx.x * blockDim.x + threadIdx.x;
    if (idx < 262144) { Sb[idx] = f2bf(Sd[idx]); return; }
    idx -= 262144;
    if (idx < 133120) { wpiece(W1, Wt1, 400, 300, 416, idx); return; }   // [320,416]
    idx -= 133120;
    if (idx < 40960)  { wpiece(W2, Wt2, 300, 100, 320, idx); return; }   // [128,320]
    idx -= 40960;
    if (idx < 40960)  { wpiece(W3, Wt3, 100, 300, 128, idx); return; }   // [320,128]
    idx -= 40960;
    if (idx < 143360) { wpiece(W4, Wt4, 300, 400, 320, idx); }           // [448,320]
}

// ---------------- L0 fused: spmm(F=2, dense Sd, f32) -> gemm K=2 + relu ----------------
// 512 threads: spmm column-split (th halves) + W0/b0/rs staged in LDS.
__global__ __launch_bounds__(512) void l0_fused(const float* __restrict__ H,
                                                const float* __restrict__ Sd0,
                                                const float* __restrict__ W0,
                                                const float* __restrict__ b0,
                                                const float* __restrict__ rs0,
                                                ushort* __restrict__ Y) {
    __shared__ float hsh[512];      // H_b [256][2], slot 255 = 0
    __shared__ float ssh[512];      // spmm result [256][2]
    __shared__ float psum[1024];    // [2 halves][256 rows][2 feats]
    __shared__ float w0s[800];      // W0 [2][400]
    __shared__ float b0s[400];
    __shared__ float rss[256];
    int b = blockIdx.x, t = threadIdx.x;
    int t0 = t & 255, th = t >> 8;
    if (th == 0) {
        if (t0 < NN) {
            hsh[t0 * 2]     = H[((size_t)b * NN + t0) * 2];
            hsh[t0 * 2 + 1] = H[((size_t)b * NN + t0) * 2 + 1];
        } else { hsh[t0 * 2] = 0.f; hsh[t0 * 2 + 1] = 0.f; }
    }
    // stage W0 / b0 / rs cooperatively (1456 floats, 512 threads)
    for (int i = t; i < 800; i += 512) w0s[i] = W0[i];
    for (int i = t; i < 400; i += 512) b0s[i] = b0[i];
    if (t < 256) rss[t] = rs0[t];
    __syncthreads();
    // partial spmm: half th covers columns [128*th, 128*th+128)
    const float4* Sr = (const float4*)(Sd0 + (size_t)t0 * 256 + th * 128);
    float s0 = 0.f, s1 = 0.f;
    #pragma unroll 8
    for (int c4 = 0; c4 < 32; ++c4) {
        float4 v = Sr[c4];
        const float2* hp = (const float2*)&hsh[th * 256 + c4 * 8];
        float2 h0 = hp[0], h1 = hp[1], h2 = hp[2], h3 = hp[3];
        s0 = fmaf(v.x, h0.x, s0); s1 = fmaf(v.x, h0.y, s1);
        s0 = fmaf(v.y, h1.x, s0); s1 = fmaf(v.y, h1.y, s1);
        s0 = fmaf(v.z, h2.x, s0); s1 = fmaf(v.z, h2.y, s1);
        s0 = fmaf(v.w, h3.x, s0); s1 = fmaf(v.w, h3.y, s1);
    }
    psum[th * 512 + t0 * 2] = s0; psum[th * 512 + t0 * 2 + 1] = s1;
    __syncthreads();
    if (th == 0) {
        ssh[t0 * 2]     = psum[t0 * 2]     + psum[512 + t0 * 2];
        ssh[t0 * 2 + 1] = psum[t0 * 2 + 1] + psum[512 + t0 * 2 + 1];
    }
    __syncthreads();
    uint* out = (uint*)(Y + (((size_t)b) << 8) * 416);
    for (int i = 0; i < 100; ++i) {
        int idx = i * 512 + t;
        int m = idx / 200, n2 = idx - m * 200;
        int n = n2 * 2;
        float x0 = ssh[m * 2], x1 = ssh[m * 2 + 1];
        float rsm = rss[m];
        float y0 = fmaf(x0, w0s[n],     fmaf(x1, w0s[400 + n],     rsm * b0s[n]));
        float y1 = fmaf(x0, w0s[n + 1], fmaf(x1, w0s[400 + n + 1], rsm * b0s[n + 1]));
        out[(size_t)m * 208 + n2] =
            (uint)f2bf(fmaxf(y0, 0.f)) | ((uint)f2bf(fmaxf(y1, 0.f)) << 16);
    }
}

// =======================================================================
// Fused layer: block = (batch b, 64-feature tile ft), 512 threads / 8 waves.
//   phase 1: Y[64f,256c] = Wt_tile @ X_b^T + bias.  Wave w owns c-rows
//            [32w,32w+32).  XOR-swizzled staging, 2-deep counted-vmcnt
//            pipeline; As staged by waves 0-3, Bs by all (per-wave vmcnt).
//   phase 2: Z[256r,64f] = relu(S @ Y); wave w owns r-rows [32w,32w+32).
// LDS 45KB (As 3x4KB + Bs 2x16KB; Ys 32KB overlay) -> 3 blocks/CU.
// =======================================================================
__global__ __launch_bounds__(512, 6) void fused_layer(const ushort* __restrict__ X,
                                                      const ushort* __restrict__ Wt,
                                                      const ushort* __restrict__ Sg,
                                                      const float* __restrict__ bias,
                                                      ushort* __restrict__ Z,
                                                      int Kpad, int Nfeat, int FsN,
                                                      int nft) {
    __shared__ __align__(16) ushort smem[22528];   // 45056 B
    ushort* As0 = smem;                  // [64][32] Wt staging, chunk%3==0
    ushort* As1 = smem + 2048;           // chunk%3==1
    ushort* As2 = smem + 4096;           // chunk%3==2
    ushort* Bs0 = smem + 6144;           // [256][32] X staging, chunk even
    ushort* Bs1 = smem + 14336;          // [256][32] X staging, chunk odd
    ushort* Ys  = smem;                  // overlay after phase 1: 8 x [64][32]

    int li = blockIdx.x;
    int x = li & 7, rr = li >> 3;
    int ft = rr % nft, b = (rr / nft) * 8 + x;
    int f0 = ft * 64;

    int t = threadIdx.x;
    int w = t >> 6, lane = t & 63;       // w = 0..7
    int frow = lane & 15, quad = lane >> 4;
    int key = (frow >> 1) & 3;           // bank-swizzle key (period 2 rows)
    int rot = (quad ^ key) * 8;          // swizzled frag-read granule offset

    // ---------------- phase 1 ----------------
    // Staged rows = 16*(const)+(lane>>2) => K=(lane>>3)&3; pre-swizzled src.
    int gsw = ((lane & 3) ^ ((lane >> 3) & 3)) * 8;
    const ushort* Xb = X + (((size_t)b) << 8) * (size_t)Kpad;
    const ushort* gB0 = Xb + (size_t)(32 * w +  0 + (lane >> 2)) * Kpad + gsw;
    const ushort* gB1 = Xb + (size_t)(32 * w + 16 + (lane >> 2)) * Kpad + gsw;
    const ushort* gA0 = Wt + (size_t)(f0 + 16 * (w & 3) + (lane >> 2)) * Kpad + gsw;

    floatx4 acc[2][4];   // acc[i][j]: i = c-tile (X rows), j = f-tile (Wt rows)
    #pragma unroll
    for (int i = 0; i < 2; ++i)
        #pragma unroll
        for (int j = 0; j < 4; ++j) acc[i][j] = (floatx4)0.f;

    int nk1 = Kpad >> 5;                 // >= 4 for all layers

    // prologue: chunk 0 -> (As0,Bs0), chunk 1 -> (As1,Bs1)
    // Bs: every wave, 2 DMAs (own 32 rows).  As: waves 0-3, 1 DMA (16 rows).
    {
        ushort* Bd = Bs0 + w * 1024;
        gl_lds16(gB0, Bd);  gl_lds16(gB1, Bd + 512);
        if (w < 4) gl_lds16(gA0, As0 + w * 512);
        ushort* Bd1 = Bs1 + w * 1024;
        gl_lds16(gB0 + 32, Bd1);  gl_lds16(gB1 + 32, Bd1 + 512);
        if (w < 4) gl_lds16(gA0 + 32, As1 + w * 512);
    }
    __builtin_amdgcn_sched_barrier(0);
    if (w < 4) asm volatile("s_waitcnt vmcnt(3)" ::: "memory");   // chunk 0 resident
    else       asm volatile("s_waitcnt vmcnt(2)" ::: "memory");
    __builtin_amdgcn_s_barrier();
    __builtin_amdgcn_sched_barrier(0);

    ushort *a0 = As0, *a1 = As1, *a2 = As2;   // a0 holds chunk ks
    ushort *bc = Bs0, *bn = Bs1;              // bc holds chunk ks

    for (int ks = 0; ks < nk1; ++ks) {
        // frag reads of chunk ks (swizzled granule = quad ^ key)
        const ushort* Ab = a0 + frow * 32 + rot;
        const ushort* Bb = bc + (w * 32 + frow) * 32 + rot;
        short8 xf[2], wf[4];
        #pragma unroll
        for (int i = 0; i < 2; ++i)
            xf[i] = u4_frag(*(const uint4*)(Bb + i * 512));   // A operand: X rows
        #pragma unroll
        for (int j = 0; j < 4; ++j)
            wf[j] = u4_frag(*(const uint4*)(Ab + j * 512));   // B operand: Wt rows
        // frag data in regs before DMA re-targets this wave's Bs region
        asm volatile("s_waitcnt lgkmcnt(0)" ::: "memory");
        __builtin_amdgcn_sched_barrier(0);
        if (ks + 2 < nk1) {              // stage chunk ks+2 (2-deep pipeline)
            int off = (ks + 2) * 32;
            ushort* Bd = bc + w * 1024;  // own 32-row region of current B buf
            gl_lds16(gB0 + off, Bd);  gl_lds16(gB1 + off, Bd + 512);
            if (w < 4) gl_lds16(gA0 + off, a2 + w * 512);   // 3rd As buffer
        }
        __builtin_amdgcn_s_setprio(1);   // T5
        #pragma unroll
        for (int i = 0; i < 2; ++i)
            #pragma unroll
            for (int j = 0; j < 4; ++j)
                acc[i][j] = __builtin_amdgcn_mfma_f32_16x16x32_bf16(xf[i], wf[j], acc[i][j], 0, 0, 0);
        __builtin_amdgcn_s_setprio(0);
        __builtin_amdgcn_sched_barrier(0);
        if (ks + 2 < nk1) {               // wait chunk ks+1 (own oldest); ks+2 in flight
            if (w < 4) asm volatile("s_waitcnt vmcnt(3)" ::: "memory");
            else       asm volatile("s_waitcnt vmcnt(2)" ::: "memory");
        } else {
            asm volatile("s_waitcnt vmcnt(0)" ::: "memory");
        }
        __builtin_amdgcn_s_barrier();
        __builtin_amdgcn_sched_barrier(0);
        ushort* ta = a0; a0 = a1; a1 = a2; a2 = ta;   // rotate As (period 3)
        ushort* tb = bc; bc = bn; bn = tb;            // swap Bs
    }

    // issue phase-2 ks=0 S loads NOW: overlap with the epilogue
    const ushort* Sp = Sg + (size_t)(w * 32 + frow) * 256 + quad * 8;
    uint4 ps[2];
    #pragma unroll
    for (int i = 0; i < 2; ++i) ps[i] = *(const uint4*)(Sp + i * 4096);

    // epilogue 1 -> Ys: c = w*32+i*16+quad*4+r (4 consecutive -> b64 write),
    // f = j*16+frow. chunk = w, gc = 2i+(quad>>1); granule position gc ^ key.
    #pragma unroll
    for (int j = 0; j < 4; ++j) {
        int f = j * 16 + frow;
        float bv = (f0 + f < Nfeat) ? bias[f0 + f] : 0.f;
        #pragma unroll
        for (int i = 0; i < 2; ++i) {
            int gc = 2 * i + (quad >> 1);
            int base = w * YCH + f * 32 + ((gc ^ key) * 8) + (quad & 1) * 4;
            uint lo = (uint)f2bf(acc[i][j][0] + bv) | ((uint)f2bf(acc[i][j][1] + bv) << 16);
            uint hi = (uint)f2bf(acc[i][j][2] + bv) | ((uint)f2bf(acc[i][j][3] + bv) << 16);
            *(uint2*)(&Ys[base]) = make_uint2(lo, hi);
        }
    }
    __syncthreads();

    // ---------------- phase 2 (no barriers, S double-buffered) ----------------
    #pragma unroll
    for (int i = 0; i < 2; ++i)
        #pragma unroll
        for (int j = 0; j < 4; ++j) acc[i][j] = (floatx4)0.f;

    for (int ks = 0; ks < 8; ++ks) {
        uint4 pn[2];
        if (ks < 7) {
            #pragma unroll
            for (int i = 0; i < 2; ++i)
                pn[i] = *(const uint4*)(Sp + i * 4096 + (ks + 1) * 32);
        }
        short8 bf[4];
        #pragma unroll
        for (int j = 0; j < 4; ++j)
            bf[j] = u4_frag(*(const uint4*)(&Ys[ks * YCH + (j * 16 + frow) * 32 + rot]));
        __builtin_amdgcn_s_setprio(1);   // T5
        #pragma unroll
        for (int i = 0; i < 2; ++i) {
            short8 af = u4_frag(ps[i]);
            #pragma unroll
            for (int j = 0; j < 4; ++j)
                acc[i][j] = __builtin_amdgcn_mfma_f32_16x16x32_bf16(af, bf[j], acc[i][j], 0, 0, 0);
        }
        __builtin_amdgcn_s_setprio(0);
        #pragma unroll
        for (int i = 0; i < 2; ++i) ps[i] = pn[i];
    }

    // epilogue 2: r = w*32+i*16+quad*4+reg, f = j*16+frow (f-tile fully valid
    // for all layers: FsN multiples of 64 and f0+64 <= FsN by grid design)
    #pragma unroll
    for (int i = 0; i < 2; ++i)
        #pragma unroll
        for (int r = 0; r < 4; ++r) {
            int rg = w * 32 + i * 16 + quad * 4 + r;
            ushort* Zr = Z + (size_t)((b << 8) + rg) * FsN + f0;
            #pragma unroll
            for (int j = 0; j < 4; ++j)
                Zr[j * 16 + frow] = f2bf(fmaxf(acc[i][j][r], 0.f));
        }
}

// ---------------- L5 fused: gemm N=2 (+bias) -> spmm(F=2, dense Sd) + relu ----------------
// 512 threads: gemm K-split + spmm column-split (th halves), LDS combine.
__global__ __launch_bounds__(512) void l5_fused(const ushort* __restrict__ X,
                                                const float* __restrict__ Sd2,
                                                const float* __restrict__ Wd2,
                                                const float* __restrict__ bd2,
                                                float* __restrict__ out) {
    __shared__ float ysh[512];
    __shared__ float psum[1024];    // [2 halves][256 rows][2 feats]
    int b = blockIdx.x, t = threadIdx.x;
    int t0 = t & 255, th = t >> 8;
    // gemm partial: half th covers i in [25*th, 25*th+25) (k = 8i..8i+7)
    const uint4* Xr = (const uint4*)(X + ((size_t)((b << 8) + t0)) * 448);
    const float4* Wp = (const float4*)Wd2;
    float a0 = th == 0 ? bd2[0] : 0.f, a1 = th == 0 ? bd2[1] : 0.f;
    for (int ii = 0; ii < 25; ++ii) {
        int i = th * 25 + ii;
        uint4 p = Xr[i];
        uint pv[4] = {p.x, p.y, p.z, p.w};
        #pragma unroll
        for (int q = 0; q < 4; ++q) {
            float x0 = bf2f((ushort)(pv[q] & 0xffffu));
            float x1 = bf2f((ushort)(pv[q] >> 16));
            float4 w = Wp[i * 4 + q];
            a0 = fmaf(x0, w.x, a0); a1 = fmaf(x0, w.y, a1);
            a0 = fmaf(x1, w.z, a0); a1 = fmaf(x1, w.w, a1);
        }
    }
    psum[th * 512 + t0 * 2] = a0; psum[th * 512 + t0 * 2 + 1] = a1;
    __syncthreads();
    if (th == 0) {
        ysh[t0 * 2]     = psum[t0 * 2]     + psum[512 + t0 * 2];
        ysh[t0 * 2 + 1] = psum[t0 * 2 + 1] + psum[512 + t0 * 2 + 1];
    }
    __syncthreads();
    // partial spmm: row t0, half th covers columns [128*th, 128*th+128)
    float s0 = 0.f, s1 = 0.f;
    if (t0 < NN) {
        const float4* Sr = (const float4*)(Sd2 + (size_t)t0 * 256 + th * 128);
        #pragma unroll 8
        for (int c4 = 0; c4 < 32; ++c4) {
            float4 v = Sr[c4];
            const float2* yp = (const float2*)&ysh[th * 256 + c4 * 8];
            float2 y0 = yp[0], y1 = yp[1], y2 = yp[2], y3 = yp[3];
            s0 = fmaf(v.x, y0.x, s0); s1 = fmaf(v.x, y0.y, s1);
            s0 = fmaf(v.y, y1.x, s0); s1 = fmaf(v.y, y1.y, s1);
            s0 = fmaf(v.z, y2.x, s0); s1 = fmaf(v.z, y2.y, s1);
            s0 = fmaf(v.w, y3.x, s0); s1 = fmaf(v.w, y3.y, s1);
        }
    }
    psum[th * 512 + t0 * 2] = s0; psum[th * 512 + t0 * 2 + 1] = s1;
    __syncthreads();
    if (th == 0 && t0 < NN) {
        out[((size_t)b * NN + t0) * 2]     = fmaxf(psum[t0 * 2]     + psum[512 + t0 * 2],     0.f);
        out[((size_t)b * NN + t0) * 2 + 1] = fmaxf(psum[t0 * 2 + 1] + psum[512 + t0 * 2 + 1], 0.f);
    }
}

extern "C" void kernel_launch(void* const* d_in, const int* in_sizes, int n_in,
                              void* d_out, int out_size, void* d_ws, size_t ws_size,
                              hipStream_t stream) {
    const float* H = (const float*)d_in[0];
    const int*   g_rows[4] = {(const int*)d_in[1], (const int*)d_in[4], (const int*)d_in[7], (const int*)d_in[10]};
    const int*   g_cols[4] = {(const int*)d_in[2], (const int*)d_in[5], (const int*)d_in[8], (const int*)d_in[11]};
    const float* g_vals[4] = {(const float*)d_in[3], (const float*)d_in[6], (const float*)d_in[9], (const float*)d_in[12]};
    const float* W0  = (const float*)d_in[13]; const float* b0  = (const float*)d_in[14];
    const float* W1  = (const float*)d_in[15]; const float* b1  = (const float*)d_in[16];
    const float* W2  = (const float*)d_in[17]; const float* b2  = (const float*)d_in[18];
    const float* Wd0 = (const float*)d_in[19]; const float* bd0 = (const float*)d_in[20];
    const float* Wd1 = (const float*)d_in[21]; const float* bd1 = (const float*)d_in[22];
    const float* Wd2 = (const float*)d_in[23]; const float* bd2 = (const float*)d_in[24];
    float* out = (float*)d_out;

    const int nnz = in_sizes[1];
    const int B   = in_sizes[0] / (NN * 2);   // 256
    const int Mp  = B * 256;                  // 65536 (padded)

    // ---- workspace (ushort units) ----
    ushort* bufA = (ushort*)d_ws;                    // N-layout [Mp, <=448]
    ushort* bufB = bufA + (size_t)Mp * 448;          // N-layout [Mp, <=320]
    ushort* Wt1 = bufB + (size_t)Mp * 320;           // [320,416]
    ushort* Wt2 = Wt1 + 320 * 416;                   // [128,320]
    ushort* Wt3 = Wt2 + 128 * 320;                   // [320,128]
    ushort* Wt4 = Wt3 + 320 * 128;                   // [448,320]
    ushort* Sb  = Wt4 + 448 * 320;                   // 4 x [256,256] bf16
    float*  rs  = (float*)(Sb + 4 * 65536);          // 4*256
    float*  Sd  = rs + 4 * 256;                      // 4*65536
    const int ZN = 4 * 256 + 4 * 65536;

    // setup: 3 launches
    zero_k<<<(ZN + 255) / 256, 256, 0, stream>>>((int*)rs, ZN);
    edge_k<<<dim3((nnz + 255) / 256, 4), 256, 0, stream>>>(
        g_rows[0], g_cols[0], g_vals[0], g_rows[1], g_cols[1], g_vals[1],
        g_rows[2], g_cols[2], g_vals[2], g_rows[3], g_cols[3], g_vals[3],
        Sd, rs, nnz);
    conv_k<<<(620544 + 255) / 256, 256, 0, stream>>>(Sd, Sb, W1, Wt1, W2, Wt2, Wd0, Wt3, Wd1, Wt4);

    // L0: [2->400] g0, commuted spmm-first, fused.  H -> bufA[Mp,416]
    l0_fused<<<B, 512, 0, stream>>>(H, Sd + 0 * 65536, W0, b0, rs + 0, bufA);

    // L1: [400->300] g0.  bufA(K416) -> bufB(FsN 320), 5 x 64-f tiles
    fused_layer<<<B * 5, 512, 0, stream>>>(bufA, Wt1, Sb + 0 * 65536, b1, bufB, 416, 300, 320, 5);
    // L2: [300->100] g1.  bufB(K320) -> bufA(FsN 128), 2 x 64-f tiles
    fused_layer<<<B * 2, 512, 0, stream>>>(bufB, Wt2, Sb + 1 * 65536, b2, bufA, 320, 100, 128, 2);
    // L3: [100->300] g3.  bufA(K128) -> bufB(FsN 320), 5 x 64-f tiles
    fused_layer<<<B * 5, 512, 0, stream>>>(bufA, Wt3, Sb + 3 * 65536, bd0, bufB, 128, 300, 320, 5);
    // L4: [300->400] g2.  bufB(K320) -> bufA(FsN 448), 7 x 64-f tiles
    fused_layer<<<B * 7, 512, 0, stream>>>(bufB, Wt4, Sb + 2 * 65536, bd1, bufA, 320, 400, 448, 7);

    // L5: [400->2] g2, fused.  bufA(stride 448, K=400) -> out[B*255,2]
    l5_fused<<<B, 512, 0, stream>>>(bufA, Sd + 2 * 65536, Wd2, bd2, out);
}

// Round 17
// 293.706 us; speedup vs baseline: 1.0882x; 1.0882x over previous
//
#include <hip/hip_runtime.h>
#include <hip/hip_bf16.h>

// 6 layers of relu(spmm(graph, x@W+b)), B=256, NN=255 nodes.
// R32 = R29 verbatim (session best, 294.3us) — terminal revert after R31's
// 64-f retile regressed (occupancy 34->51 but MfmaUtil 29->21: thinner
// tiles halve MFMA-per-sync; intensity loss beats occupancy gain).
// Final structure: 128-f tiles, 8 waves/512 thr, 2 blocks/CU (16 waves/CU);
// phase-1 global_load_lds staging (As triple-, Bs double-buffered, linear
// dest + pre-swizzled source), 2-deep counted vmcnt(3) pipeline, one
// barrier/k-step; XOR bank swizzle key (frow>>1)&3 on staging + Ys
// (conflicts 5.9M->524K); T5 setprio around MFMA clusters; scalar-cast
// f2bf; l0/l5 512-thread split-K/split-column with LDS combines.

#define NN 255
#define YCH 4096           // ushorts per Y chunk: 128 rows * 32

typedef __attribute__((ext_vector_type(8))) short short8;
typedef __attribute__((ext_vector_type(4))) float floatx4;

__device__ __forceinline__ float bf2f(ushort u) {
    union { uint u; float f; } c; c.u = ((uint)u) << 16; return c.f;
}
// native scalar cast (fptrunc, RNE) -> backend emits v_cvt_pk_bf16_f32
__device__ __forceinline__ ushort f2bf(float f) {
    __bf16 h = (__bf16)f;
    ushort u; __builtin_memcpy(&u, &h, 2); return u;
}
__device__ __forceinline__ short8 u4_frag(uint4 v) {
    union { uint4 u; short8 s; } c; c.u = v; return c.s;
}
// global -> LDS DMA, 16B per lane (dest = lds + lane*16, src per-lane)
__device__ __forceinline__ void gl_lds16(const ushort* g, ushort* l) {
    __builtin_amdgcn_global_load_lds(
        (const __attribute__((address_space(1))) void*)g,
        (__attribute__((address_space(3))) void*)l, 16, 0, 0);
}

// ---------------- graph preprocessing ----------------
__global__ void zero_k(int* p, int n) {
    int i = blockIdx.x * blockDim.x + threadIdx.x;
    if (i < n) p[i] = 0;
}

// per-edge: dense-S scatter + rowsum (f32 atomics)
__global__ void edge_k(const int* __restrict__ r0, const int* __restrict__ c0, const float* __restrict__ v0,
                       const int* __restrict__ r1, const int* __restrict__ c1, const float* __restrict__ v1,
                       const int* __restrict__ r2, const int* __restrict__ c2, const float* __restrict__ v2,
                       const int* __restrict__ r3, const int* __restrict__ c3, const float* __restrict__ v3,
                       float* Sd, float* rs, int nnz) {
    int gi = blockIdx.y;
    int e = blockIdx.x * blockDim.x + threadIdx.x;
    if (e >= nnz) return;
    const int* rr = gi == 0 ? r0 : gi == 1 ? r1 : gi == 2 ? r2 : r3;
    const int* cc = gi == 0 ? c0 : gi == 1 ? c1 : gi == 2 ? c2 : c3;
    const float* vv = gi == 0 ? v0 : gi == 1 ? v1 : gi == 2 ? v2 : v3;
    int r = rr[e], c = cc[e];
    float v = vv[e];
    atomicAdd(&Sd[gi * 65536 + r * 256 + c], v);
    atomicAdd(&rs[gi * 256 + r], v);
}

// merged converts: Sd->Sb (bf16) then 4 weight transposes (ladder on idx)
__device__ __forceinline__ void wpiece(const float* __restrict__ W, ushort* __restrict__ Wt,
                                       int K, int N, int Kpad, int idx) {
    int n = idx / Kpad, k = idx - n * Kpad;
    float v = (n < N && k < K) ? W[(size_t)k * N + n] : 0.f;
    Wt[idx] = f2bf(v);
}

__global__ void conv_k(const float* __restrict__ Sd, ushort* __restrict__ Sb,
                       const float* __restrict__ W1, ushort* __restrict__ Wt1,
                       const float* __restrict__ W2, ushort* __restrict__ Wt2,
                       const float* __restrict__ W3, ushort* __restrict__ Wt3,
                       const float* __restrict__ W4, ushort* __restrict__ Wt4) {
    int idx = blockIdx.x * blockDim.x + threadIdx.x;
    if (idx < 262144) { Sb[idx] = f2bf(Sd[idx]); return; }
    idx -= 262144;
    if (idx < 159744) { wpiece(W1, Wt1, 400, 300, 416, idx); return; }   // [384,416]
    idx -= 159744;
    if (idx < 40960)  { wpiece(W2, Wt2, 300, 100, 320, idx); return; }   // [128,320]
    idx -= 40960;
    if (idx < 49152)  { wpiece(W3, Wt3, 100, 300, 128, idx); return; }   // [384,128]
    idx -= 49152;
    if (idx < 163840) { wpiece(W4, Wt4, 300, 400, 320, idx); }           // [512,320]
}

// ---------------- L0 fused: spmm(F=2, dense Sd, f32) -> gemm K=2 + relu ----------------
// 512 threads: spmm column-split (th halves) + W0/b0/rs staged in LDS.
__global__ __launch_bounds__(512) void l0_fused(const float* __restrict__ H,
                                                const float* __restrict__ Sd0,
                                                const float* __restrict__ W0,
                                                const float* __restrict__ b0,
                                                const float* __restrict__ rs0,
                                                ushort* __restrict__ Y) {
    __shared__ float hsh[512];      // H_b [256][2], slot 255 = 0
    __shared__ float ssh[512];      // spmm result [256][2]
    __shared__ float psum[1024];    // [2 halves][256 rows][2 feats]
    __shared__ float w0s[800];      // W0 [2][400]
    __shared__ float b0s[400];
    __shared__ float rss[256];
    int b = blockIdx.x, t = threadIdx.x;
    int t0 = t & 255, th = t >> 8;
    if (th == 0) {
        if (t0 < NN) {
            hsh[t0 * 2]     = H[((size_t)b * NN + t0) * 2];
            hsh[t0 * 2 + 1] = H[((size_t)b * NN + t0) * 2 + 1];
        } else { hsh[t0 * 2] = 0.f; hsh[t0 * 2 + 1] = 0.f; }
    }
    // stage W0 / b0 / rs cooperatively (1456 floats, 512 threads)
    for (int i = t; i < 800; i += 512) w0s[i] = W0[i];
    for (int i = t; i < 400; i += 512) b0s[i] = b0[i];
    if (t < 256) rss[t] = rs0[t];
    __syncthreads();
    // partial spmm: half th covers columns [128*th, 128*th+128)
    const float4* Sr = (const float4*)(Sd0 + (size_t)t0 * 256 + th * 128);
    float s0 = 0.f, s1 = 0.f;
    #pragma unroll 8
    for (int c4 = 0; c4 < 32; ++c4) {
        float4 v = Sr[c4];
        const float2* hp = (const float2*)&hsh[th * 256 + c4 * 8];
        float2 h0 = hp[0], h1 = hp[1], h2 = hp[2], h3 = hp[3];
        s0 = fmaf(v.x, h0.x, s0); s1 = fmaf(v.x, h0.y, s1);
        s0 = fmaf(v.y, h1.x, s0); s1 = fmaf(v.y, h1.y, s1);
        s0 = fmaf(v.z, h2.x, s0); s1 = fmaf(v.z, h2.y, s1);
        s0 = fmaf(v.w, h3.x, s0); s1 = fmaf(v.w, h3.y, s1);
    }
    psum[th * 512 + t0 * 2] = s0; psum[th * 512 + t0 * 2 + 1] = s1;
    __syncthreads();
    if (th == 0) {
        ssh[t0 * 2]     = psum[t0 * 2]     + psum[512 + t0 * 2];
        ssh[t0 * 2 + 1] = psum[t0 * 2 + 1] + psum[512 + t0 * 2 + 1];
    }
    __syncthreads();
    uint* out = (uint*)(Y + (((size_t)b) << 8) * 416);
    for (int i = 0; i < 100; ++i) {
        int idx = i * 512 + t;
        int m = idx / 200, n2 = idx - m * 200;
        int n = n2 * 2;
        float x0 = ssh[m * 2], x1 = ssh[m * 2 + 1];
        float rsm = rss[m];
        float y0 = fmaf(x0, w0s[n],     fmaf(x1, w0s[400 + n],     rsm * b0s[n]));
        float y1 = fmaf(x0, w0s[n + 1], fmaf(x1, w0s[400 + n + 1], rsm * b0s[n + 1]));
        out[(size_t)m * 208 + n2] =
            (uint)f2bf(fmaxf(y0, 0.f)) | ((uint)f2bf(fmaxf(y1, 0.f)) << 16);
    }
}

// =======================================================================
// Fused layer: block = (batch b, 128-feature tile ft), 512 threads / 8 waves.
//   phase 1: Y[128f,256c] = Wt_tile @ X_b^T + bias.  Wave w owns c-rows
//            [32w,32w+32).  XOR-swizzled As/Bs staging (linear LDS dest,
//            pre-swizzled global source), 2-deep counted-vmcnt pipeline.
//   phase 2: Z[256r,128f] = relu(S @ Y); wave w owns r-rows [32w,32w+32).
// LDS bank swizzle: granule g of row r stored at position g ^ ((r>>1)&3).
// =======================================================================
__global__ __launch_bounds__(512, 4) void fused_layer(const ushort* __restrict__ X,
                                                      const ushort* __restrict__ Wt,
                                                      const ushort* __restrict__ Sg,
                                                      const float* __restrict__ bias,
                                                      ushort* __restrict__ Z,
                                                      int Kpad, int Nfeat, int FsN,
                                                      int nft) {
    __shared__ __align__(16) ushort smem[32768];   // 65536 B
    ushort* As0 = smem;                  // [128][32] Wt staging, chunk%3==0
    ushort* As1 = smem + 4096;           // chunk%3==1
    ushort* As2 = smem + 8192;           // chunk%3==2
    ushort* Bs0 = smem + 12288;          // [256][32] X staging, chunk even
    ushort* Bs1 = smem + 20480;          // [256][32] X staging, chunk odd
    ushort* Ys  = smem;                  // overlay after phase 1: 8 x [128][32]

    int li = blockIdx.x;
    int x = li & 7, rr = li >> 3;
    int ft = rr % nft, b = (rr / nft) * 8 + x;
    int f0 = ft * 128;

    int t = threadIdx.x;
    int w = t >> 6, lane = t & 63;       // w = 0..7
    int frow = lane & 15, quad = lane >> 4;
    int key = (frow >> 1) & 3;           // bank-swizzle key (period 2 rows)
    int rot = (quad ^ key) * 8;          // swizzled frag-read granule offset

    // ---------------- phase 1 ----------------
    int gsw = ((lane & 3) ^ ((lane >> 3) & 3)) * 8;
    const ushort* Xb = X + (((size_t)b) << 8) * (size_t)Kpad;
    const ushort* gB0 = Xb + (size_t)(32 * w +  0 + (lane >> 2)) * Kpad + gsw;
    const ushort* gB1 = Xb + (size_t)(32 * w + 16 + (lane >> 2)) * Kpad + gsw;
    const ushort* gA0 = Wt + (size_t)(f0 + 16 * w + (lane >> 2)) * Kpad + gsw;

    floatx4 acc[2][8];   // acc[i][j]: i = c-tile (X rows), j = f-tile (Wt rows)
    #pragma unroll
    for (int i = 0; i < 2; ++i)
        #pragma unroll
        for (int j = 0; j < 8; ++j) acc[i][j] = (floatx4)0.f;

    int nk1 = Kpad >> 5;                 // >= 4 for all layers

    // prologue: chunk 0 -> (As0,Bs0), chunk 1 -> (As1,Bs1); 3 DMAs/wave each
    {
        ushort* Bd = Bs0 + w * 1024;
        gl_lds16(gB0, Bd);  gl_lds16(gB1, Bd + 512);
        gl_lds16(gA0, As0 + w * 512);
        ushort* Bd1 = Bs1 + w * 1024;
        gl_lds16(gB0 + 32, Bd1);  gl_lds16(gB1 + 32, Bd1 + 512);
        gl_lds16(gA0 + 32, As1 + w * 512);
    }
    __builtin_amdgcn_sched_barrier(0);
    asm volatile("s_waitcnt vmcnt(3)" ::: "memory");   // chunk 0 resident
    __builtin_amdgcn_s_barrier();
    __builtin_amdgcn_sched_barrier(0);

    ushort *a0 = As0, *a1 = As1, *a2 = As2;   // a0 holds chunk ks
    ushort *bc = Bs0, *bn = Bs1;              // bc holds chunk ks

    for (int ks = 0; ks < nk1; ++ks) {
        // frag reads of chunk ks (swizzled granule = quad ^ key)
        const ushort* Ab = a0 + frow * 32 + rot;
        const ushort* Bb = bc + (w * 32 + frow) * 32 + rot;
        short8 xf[2], wf[8];
        #pragma unroll
        for (int i = 0; i < 2; ++i)
            xf[i] = u4_frag(*(const uint4*)(Bb + i * 512));   // A operand: X rows
        #pragma unroll
        for (int j = 0; j < 8; ++j)
            wf[j] = u4_frag(*(const uint4*)(Ab + j * 512));   // B operand: Wt rows
        // frag data in regs before DMA re-targets this wave's Bs region
        asm volatile("s_waitcnt lgkmcnt(0)" ::: "memory");
        __builtin_amdgcn_sched_barrier(0);
        if (ks + 2 < nk1) {              // stage chunk ks+2 (2-deep pipeline)
            int off = (ks + 2) * 32;
            ushort* Bd = bc + w * 1024;  // own 32-row region of current B buf
            gl_lds16(gB0 + off, Bd);  gl_lds16(gB1 + off, Bd + 512);
            gl_lds16(gA0 + off, a2 + w * 512);   // 3rd As buffer
        }
        __builtin_amdgcn_s_setprio(1);   // T5
        #pragma unroll
        for (int i = 0; i < 2; ++i)
            #pragma unroll
            for (int j = 0; j < 8; ++j)
                acc[i][j] = __builtin_amdgcn_mfma_f32_16x16x32_bf16(xf[i], wf[j], acc[i][j], 0, 0, 0);
        __builtin_amdgcn_s_setprio(0);
        __builtin_amdgcn_sched_barrier(0);
        if (ks + 2 < nk1)                 // wait chunk ks+1 (3 oldest); ks+2 in flight
            asm volatile("s_waitcnt vmcnt(3)" ::: "memory");
        else
            asm volatile("s_waitcnt vmcnt(0)" ::: "memory");
        __builtin_amdgcn_s_barrier();
        __builtin_amdgcn_sched_barrier(0);
        ushort* ta = a0; a0 = a1; a1 = a2; a2 = ta;   // rotate As (period 3)
        ushort* tb = bc; bc = bn; bn = tb;            // swap Bs
    }

    // issue phase-2 ks=0 S loads NOW: overlap with the epilogue
    const ushort* Sp = Sg + (size_t)(w * 32 + frow) * 256 + quad * 8;
    uint4 ps[2];
    #pragma unroll
    for (int i = 0; i < 2; ++i) ps[i] = *(const uint4*)(Sp + i * 4096);

    // epilogue 1 -> Ys: c = w*32+i*16+quad*4+r (4 consecutive -> b64 write),
    // f = j*16+frow. chunk = w, gc = 2i+(quad>>1); granule position gc ^ key.
    #pragma unroll
    for (int j = 0; j < 8; ++j) {
        int f = j * 16 + frow;
        float bv = (f0 + f < Nfeat) ? bias[f0 + f] : 0.f;
        #pragma unroll
        for (int i = 0; i < 2; ++i) {
            int gc = 2 * i + (quad >> 1);
            int base = w * YCH + f * 32 + ((gc ^ key) * 8) + (quad & 1) * 4;
            uint lo = (uint)f2bf(acc[i][j][0] + bv) | ((uint)f2bf(acc[i][j][1] + bv) << 16);
            uint hi = (uint)f2bf(acc[i][j][2] + bv) | ((uint)f2bf(acc[i][j][3] + bv) << 16);
            *(uint2*)(&Ys[base]) = make_uint2(lo, hi);
        }
    }
    __syncthreads();

    // ---------------- phase 2 (no barriers, S double-buffered) ----------------
    #pragma unroll
    for (int i = 0; i < 2; ++i)
        #pragma unroll
        for (int j = 0; j < 8; ++j) acc[i][j] = (floatx4)0.f;

    for (int ks = 0; ks < 8; ++ks) {
        uint4 pn[2];
        if (ks < 7) {
            #pragma unroll
            for (int i = 0; i < 2; ++i)
                pn[i] = *(const uint4*)(Sp + i * 4096 + (ks + 1) * 32);
        }
        short8 bf[8];
        #pragma unroll
        for (int j = 0; j < 8; ++j)
            bf[j] = u4_frag(*(const uint4*)(&Ys[ks * YCH + (j * 16 + frow) * 32 + rot]));
        __builtin_amdgcn_s_setprio(1);   // T5
        #pragma unroll
        for (int i = 0; i < 2; ++i) {
            short8 af = u4_frag(ps[i]);
            #pragma unroll
            for (int j = 0; j < 8; ++j)
                acc[i][j] = __builtin_amdgcn_mfma_f32_16x16x32_bf16(af, bf[j], acc[i][j], 0, 0, 0);
        }
        __builtin_amdgcn_s_setprio(0);
        #pragma unroll
        for (int i = 0; i < 2; ++i) ps[i] = pn[i];
    }

    // epilogue 2: r = w*32+i*16+quad*4+reg, f = j*16+frow; guard f-tile pad
    #pragma unroll
    for (int i = 0; i < 2; ++i)
        #pragma unroll
        for (int r = 0; r < 4; ++r) {
            int rg = w * 32 + i * 16 + quad * 4 + r;
            ushort* Zr = Z + (size_t)((b << 8) + rg) * FsN + f0;
            #pragma unroll
            for (int j = 0; j < 8; ++j)
                if (f0 + j * 16 < FsN)
                    Zr[j * 16 + frow] = f2bf(fmaxf(acc[i][j][r], 0.f));
        }
}

// ---------------- L5 fused: gemm N=2 (+bias) -> spmm(F=2, dense Sd) + relu ----------------
// 512 threads: gemm K-split + spmm column-split (th halves), LDS combine.
__global__ __launch_bounds__(512) void l5_fused(const ushort* __restrict__ X,
                                                const float* __restrict__ Sd2,
                                                const float* __restrict__ Wd2,
                                                const float* __restrict__ bd2,
                                                float* __restrict__ out) {
    __shared__ float ysh[512];
    __shared__ float psum[1024];    // [2 halves][256 rows][2 feats]
    int b = blockIdx.x, t = threadIdx.x;
    int t0 = t & 255, th = t >> 8;
    // gemm partial: half th covers i in [25*th, 25*th+25) (k = 8i..8i+7)
    const uint4* Xr = (const uint4*)(X + ((size_t)((b << 8) + t0)) * 448);
    const float4* Wp = (const float4*)Wd2;
    float a0 = th == 0 ? bd2[0] : 0.f, a1 = th == 0 ? bd2[1] : 0.f;
    for (int ii = 0; ii < 25; ++ii) {
        int i = th * 25 + ii;
        uint4 p = Xr[i];
        uint pv[4] = {p.x, p.y, p.z, p.w};
        #pragma unroll
        for (int q = 0; q < 4; ++q) {
            float x0 = bf2f((ushort)(pv[q] & 0xffffu));
            float x1 = bf2f((ushort)(pv[q] >> 16));
            float4 w = Wp[i * 4 + q];
            a0 = fmaf(x0, w.x, a0); a1 = fmaf(x0, w.y, a1);
            a0 = fmaf(x1, w.z, a0); a1 = fmaf(x1, w.w, a1);
        }
    }
    psum[th * 512 + t0 * 2] = a0; psum[th * 512 + t0 * 2 + 1] = a1;
    __syncthreads();
    if (th == 0) {
        ysh[t0 * 2]     = psum[t0 * 2]     + psum[512 + t0 * 2];
        ysh[t0 * 2 + 1] = psum[t0 * 2 + 1] + psum[512 + t0 * 2 + 1];
    }
    __syncthreads();
    // partial spmm: row t0, half th covers columns [128*th, 128*th+128)
    float s0 = 0.f, s1 = 0.f;
    if (t0 < NN) {
        const float4* Sr = (const float4*)(Sd2 + (size_t)t0 * 256 + th * 128);
        #pragma unroll 8
        for (int c4 = 0; c4 < 32; ++c4) {
            float4 v = Sr[c4];
            const float2* yp = (const float2*)&ysh[th * 256 + c4 * 8];
            float2 y0 = yp[0], y1 = yp[1], y2 = yp[2], y3 = yp[3];
            s0 = fmaf(v.x, y0.x, s0); s1 = fmaf(v.x, y0.y, s1);
            s0 = fmaf(v.y, y1.x, s0); s1 = fmaf(v.y, y1.y, s1);
            s0 = fmaf(v.z, y2.x, s0); s1 = fmaf(v.z, y2.y, s1);
            s0 = fmaf(v.w, y3.x, s0); s1 = fmaf(v.w, y3.y, s1);
        }
    }
    psum[th * 512 + t0 * 2] = s0; psum[th * 512 + t0 * 2 + 1] = s1;
    __syncthreads();
    if (th == 0 && t0 < NN) {
        out[((size_t)b * NN + t0) * 2]     = fmaxf(psum[t0 * 2]     + psum[512 + t0 * 2],     0.f);
        out[((size_t)b * NN + t0) * 2 + 1] = fmaxf(psum[t0 * 2 + 1] + psum[512 + t0 * 2 + 1], 0.f);
    }
}

extern "C" void kernel_launch(void* const* d_in, const int* in_sizes, int n_in,
                              void* d_out, int out_size, void* d_ws, size_t ws_size,
                              hipStream_t stream) {
    const float* H = (const float*)d_in[0];
    const int*   g_rows[4] = {(const int*)d_in[1], (const int*)d_in[4], (const int*)d_in[7], (const int*)d_in[10]};
    const int*   g_cols[4] = {(const int*)d_in[2], (const int*)d_in[5], (const int*)d_in[8], (const int*)d_in[11]};
    const float* g_vals[4] = {(const float*)d_in[3], (const float*)d_in[6], (const float*)d_in[9], (const float*)d_in[12]};
    const float* W0  = (const float*)d_in[13]; const float* b0  = (const float*)d_in[14];
    const float* W1  = (const float*)d_in[15]; const float* b1  = (const float*)d_in[16];
    const float* W2  = (const float*)d_in[17]; const float* b2  = (const float*)d_in[18];
    const float* Wd0 = (const float*)d_in[19]; const float* bd0 = (const float*)d_in[20];
    const float* Wd1 = (const float*)d_in[21]; const float* bd1 = (const float*)d_in[22];
    const float* Wd2 = (const float*)d_in[23]; const float* bd2 = (const float*)d_in[24];
    float* out = (float*)d_out;

    const int nnz = in_sizes[1];
    const int B   = in_sizes[0] / (NN * 2);   // 256
    const int Mp  = B * 256;                  // 65536 (padded)

    // ---- workspace (ushort units) ----
    ushort* bufA = (ushort*)d_ws;                    // N-layout [Mp, <=448]
    ushort* bufB = bufA + (size_t)Mp * 448;          // N-layout [Mp, <=320]
    ushort* Wt1 = bufB + (size_t)Mp * 320;           // [384,416]
    ushort* Wt2 = Wt1 + 384 * 416;                   // [128,320]
    ushort* Wt3 = Wt2 + 128 * 320;                   // [384,128]
    ushort* Wt4 = Wt3 + 384 * 128;                   // [512,320]
    ushort* Sb  = Wt4 + 512 * 320;                   // 4 x [256,256] bf16
    float*  rs  = (float*)(Sb + 4 * 65536);          // 4*256
    float*  Sd  = rs + 4 * 256;                      // 4*65536
    const int ZN = 4 * 256 + 4 * 65536;

    // setup: 3 launches
    zero_k<<<(ZN + 255) / 256, 256, 0, stream>>>((int*)rs, ZN);
    edge_k<<<dim3((nnz + 255) / 256, 4), 256, 0, stream>>>(
        g_rows[0], g_cols[0], g_vals[0], g_rows[1], g_cols[1], g_vals[1],
        g_rows[2], g_cols[2], g_vals[2], g_rows[3], g_cols[3], g_vals[3],
        Sd, rs, nnz);
    conv_k<<<(675840 + 255) / 256, 256, 0, stream>>>(Sd, Sb, W1, Wt1, W2, Wt2, Wd0, Wt3, Wd1, Wt4);

    // L0: [2->400] g0, commuted spmm-first, fused.  H -> bufA[Mp,416]
    l0_fused<<<B, 512, 0, stream>>>(H, Sd + 0 * 65536, W0, b0, rs + 0, bufA);

    // L1: [400->300] g0.  bufA(K416) -> bufB(FsN 320), 3 x 128-f tiles
    fused_layer<<<B * 3, 512, 0, stream>>>(bufA, Wt1, Sb + 0 * 65536, b1, bufB, 416, 300, 320, 3);
    // L2: [300->100] g1.  bufB(K320) -> bufA(FsN 128), 1 x 128-f tile
    fused_layer<<<B * 1, 512, 0, stream>>>(bufB, Wt2, Sb + 1 * 65536, b2, bufA, 320, 100, 128, 1);
    // L3: [100->300] g3.  bufA(K128) -> bufB(FsN 320), 3 x 128-f tiles
    fused_layer<<<B * 3, 512, 0, stream>>>(bufA, Wt3, Sb + 3 * 65536, bd0, bufB, 128, 300, 320, 3);
    // L4: [300->400] g2.  bufB(K320) -> bufA(FsN 448), 4 x 128-f tiles
    fused_layer<<<B * 4, 512, 0, stream>>>(bufB, Wt4, Sb + 2 * 65536, bd1, bufA, 320, 400, 448, 4);

    // L5: [400->2] g2, fused.  bufA(stride 448, K=400) -> out[B*255,2]
    l5_fused<<<B, 512, 0, stream>>>(bufA, Sd + 2 * 65536, Wd2, bd2, out);
}

// Round 18
// 293.023 us; speedup vs baseline: 1.0908x; 1.0023x over previous
//
#include <hip/hip_runtime.h>
#include <hip/hip_bf16.h>

// 6 layers of relu(spmm(graph, x@W+b)), B=256, NN=255 nodes.
// R33 = R32/R29 (best, 293.7us) + ONE isolated change: Bs triple-buffered
// (was double).  The in-loop chunk-ks+2 DMA previously targeted the buffer
// being READ (bc), forcing an explicit s_waitcnt lgkmcnt(0) (full drain of
// 10 ds_read_b128, ~120+cyc) serialized before the DMA issue every k-step.
// With 3 Bs buffers the DMA targets b2 (disjoint from all reads) -> drain
// and its sched_barrier deleted; compiler's automatic lgkm waits before
// MFMA handle the frag-read dependence; DMA issues ~100+cyc earlier/step.
// LDS 64->72KB (3x8KB As + 3x16KB Bs; Ys 64KB overlay); 2x72=144<=160KB/CU
// -> occupancy unchanged (2 blocks/CU).  vmcnt ledger unchanged: 3 DMAs/
// chunk, 2-deep, vmcnt(3) = chunk ks+1 resident; cross-wave As visibility
// via the k-step barrier exactly as before.  Rest byte-identical to R32.

#define NN 255
#define YCH 4096           // ushorts per Y chunk: 128 rows * 32

typedef __attribute__((ext_vector_type(8))) short short8;
typedef __attribute__((ext_vector_type(4))) float floatx4;

__device__ __forceinline__ float bf2f(ushort u) {
    union { uint u; float f; } c; c.u = ((uint)u) << 16; return c.f;
}
// native scalar cast (fptrunc, RNE) -> backend emits v_cvt_pk_bf16_f32
__device__ __forceinline__ ushort f2bf(float f) {
    __bf16 h = (__bf16)f;
    ushort u; __builtin_memcpy(&u, &h, 2); return u;
}
__device__ __forceinline__ short8 u4_frag(uint4 v) {
    union { uint4 u; short8 s; } c; c.u = v; return c.s;
}
// global -> LDS DMA, 16B per lane (dest = lds + lane*16, src per-lane)
__device__ __forceinline__ void gl_lds16(const ushort* g, ushort* l) {
    __builtin_amdgcn_global_load_lds(
        (const __attribute__((address_space(1))) void*)g,
        (__attribute__((address_space(3))) void*)l, 16, 0, 0);
}

// ---------------- graph preprocessing ----------------
__global__ void zero_k(int* p, int n) {
    int i = blockIdx.x * blockDim.x + threadIdx.x;
    if (i < n) p[i] = 0;
}

// per-edge: dense-S scatter + rowsum (f32 atomics)
__global__ void edge_k(const int* __restrict__ r0, const int* __restrict__ c0, const float* __restrict__ v0,
                       const int* __restrict__ r1, const int* __restrict__ c1, const float* __restrict__ v1,
                       const int* __restrict__ r2, const int* __restrict__ c2, const float* __restrict__ v2,
                       const int* __restrict__ r3, const int* __restrict__ c3, const float* __restrict__ v3,
                       float* Sd, float* rs, int nnz) {
    int gi = blockIdx.y;
    int e = blockIdx.x * blockDim.x + threadIdx.x;
    if (e >= nnz) return;
    const int* rr = gi == 0 ? r0 : gi == 1 ? r1 : gi == 2 ? r2 : r3;
    const int* cc = gi == 0 ? c0 : gi == 1 ? c1 : gi == 2 ? c2 : c3;
    const float* vv = gi == 0 ? v0 : gi == 1 ? v1 : gi == 2 ? v2 : v3;
    int r = rr[e], c = cc[e];
    float v = vv[e];
    atomicAdd(&Sd[gi * 65536 + r * 256 + c], v);
    atomicAdd(&rs[gi * 256 + r], v);
}

// merged converts: Sd->Sb (bf16) then 4 weight transposes (ladder on idx)
__device__ __forceinline__ void wpiece(const float* __restrict__ W, ushort* __restrict__ Wt,
                                       int K, int N, int Kpad, int idx) {
    int n = idx / Kpad, k = idx - n * Kpad;
    float v = (n < N && k < K) ? W[(size_t)k * N + n] : 0.f;
    Wt[idx] = f2bf(v);
}

__global__ void conv_k(const float* __restrict__ Sd, ushort* __restrict__ Sb,
                       const float* __restrict__ W1, ushort* __restrict__ Wt1,
                       const float* __restrict__ W2, ushort* __restrict__ Wt2,
                       const float* __restrict__ W3, ushort* __restrict__ Wt3,
                       const float* __restrict__ W4, ushort* __restrict__ Wt4) {
    int idx = blockIdx.x * blockDim.x + threadIdx.x;
    if (idx < 262144) { Sb[idx] = f2bf(Sd[idx]); return; }
    idx -= 262144;
    if (idx < 159744) { wpiece(W1, Wt1, 400, 300, 416, idx); return; }   // [384,416]
    idx -= 159744;
    if (idx < 40960)  { wpiece(W2, Wt2, 300, 100, 320, idx); return; }   // [128,320]
    idx -= 40960;
    if (idx < 49152)  { wpiece(W3, Wt3, 100, 300, 128, idx); return; }   // [384,128]
    idx -= 49152;
    if (idx < 163840) { wpiece(W4, Wt4, 300, 400, 320, idx); }           // [512,320]
}

// ---------------- L0 fused: spmm(F=2, dense Sd, f32) -> gemm K=2 + relu ----------------
// 512 threads: spmm column-split (th halves) + W0/b0/rs staged in LDS.
__global__ __launch_bounds__(512) void l0_fused(const float* __restrict__ H,
                                                const float* __restrict__ Sd0,
                                                const float* __restrict__ W0,
                                                const float* __restrict__ b0,
                                                const float* __restrict__ rs0,
                                                ushort* __restrict__ Y) {
    __shared__ float hsh[512];      // H_b [256][2], slot 255 = 0
    __shared__ float ssh[512];      // spmm result [256][2]
    __shared__ float psum[1024];    // [2 halves][256 rows][2 feats]
    __shared__ float w0s[800];      // W0 [2][400]
    __shared__ float b0s[400];
    __shared__ float rss[256];
    int b = blockIdx.x, t = threadIdx.x;
    int t0 = t & 255, th = t >> 8;
    if (th == 0) {
        if (t0 < NN) {
            hsh[t0 * 2]     = H[((size_t)b * NN + t0) * 2];
            hsh[t0 * 2 + 1] = H[((size_t)b * NN + t0) * 2 + 1];
        } else { hsh[t0 * 2] = 0.f; hsh[t0 * 2 + 1] = 0.f; }
    }
    // stage W0 / b0 / rs cooperatively (1456 floats, 512 threads)
    for (int i = t; i < 800; i += 512) w0s[i] = W0[i];
    for (int i = t; i < 400; i += 512) b0s[i] = b0[i];
    if (t < 256) rss[t] = rs0[t];
    __syncthreads();
    // partial spmm: half th covers columns [128*th, 128*th+128)
    const float4* Sr = (const float4*)(Sd0 + (size_t)t0 * 256 + th * 128);
    float s0 = 0.f, s1 = 0.f;
    #pragma unroll 8
    for (int c4 = 0; c4 < 32; ++c4) {
        float4 v = Sr[c4];
        const float2* hp = (const float2*)&hsh[th * 256 + c4 * 8];
        float2 h0 = hp[0], h1 = hp[1], h2 = hp[2], h3 = hp[3];
        s0 = fmaf(v.x, h0.x, s0); s1 = fmaf(v.x, h0.y, s1);
        s0 = fmaf(v.y, h1.x, s0); s1 = fmaf(v.y, h1.y, s1);
        s0 = fmaf(v.z, h2.x, s0); s1 = fmaf(v.z, h2.y, s1);
        s0 = fmaf(v.w, h3.x, s0); s1 = fmaf(v.w, h3.y, s1);
    }
    psum[th * 512 + t0 * 2] = s0; psum[th * 512 + t0 * 2 + 1] = s1;
    __syncthreads();
    if (th == 0) {
        ssh[t0 * 2]     = psum[t0 * 2]     + psum[512 + t0 * 2];
        ssh[t0 * 2 + 1] = psum[t0 * 2 + 1] + psum[512 + t0 * 2 + 1];
    }
    __syncthreads();
    uint* out = (uint*)(Y + (((size_t)b) << 8) * 416);
    for (int i = 0; i < 100; ++i) {
        int idx = i * 512 + t;
        int m = idx / 200, n2 = idx - m * 200;
        int n = n2 * 2;
        float x0 = ssh[m * 2], x1 = ssh[m * 2 + 1];
        float rsm = rss[m];
        float y0 = fmaf(x0, w0s[n],     fmaf(x1, w0s[400 + n],     rsm * b0s[n]));
        float y1 = fmaf(x0, w0s[n + 1], fmaf(x1, w0s[400 + n + 1], rsm * b0s[n + 1]));
        out[(size_t)m * 208 + n2] =
            (uint)f2bf(fmaxf(y0, 0.f)) | ((uint)f2bf(fmaxf(y1, 0.f)) << 16);
    }
}

// =======================================================================
// Fused layer: block = (batch b, 128-feature tile ft), 512 threads / 8 waves.
//   phase 1: Y[128f,256c] = Wt_tile @ X_b^T + bias.  Wave w owns c-rows
//            [32w,32w+32).  XOR-swizzled As/Bs staging (linear LDS dest,
//            pre-swizzled global source), 2-deep counted-vmcnt pipeline,
//            BOTH As and Bs triple-buffered -> no in-loop lgkm drain.
//   phase 2: Z[256r,128f] = relu(S @ Y); wave w owns r-rows [32w,32w+32).
// LDS bank swizzle: granule g of row r stored at position g ^ ((r>>1)&3).
// =======================================================================
__global__ __launch_bounds__(512, 4) void fused_layer(const ushort* __restrict__ X,
                                                      const ushort* __restrict__ Wt,
                                                      const ushort* __restrict__ Sg,
                                                      const float* __restrict__ bias,
                                                      ushort* __restrict__ Z,
                                                      int Kpad, int Nfeat, int FsN,
                                                      int nft) {
    __shared__ __align__(16) ushort smem[36864];   // 73728 B
    ushort* As0 = smem;                  // [128][32] Wt staging, chunk%3==0
    ushort* As1 = smem + 4096;           // chunk%3==1
    ushort* As2 = smem + 8192;           // chunk%3==2
    ushort* Bs0 = smem + 12288;          // [256][32] X staging, chunk%3==0
    ushort* Bs1 = smem + 20480;          // chunk%3==1
    ushort* Bs2 = smem + 28672;          // chunk%3==2
    ushort* Ys  = smem;                  // overlay after phase 1: 8 x [128][32]

    int li = blockIdx.x;
    int x = li & 7, rr = li >> 3;
    int ft = rr % nft, b = (rr / nft) * 8 + x;
    int f0 = ft * 128;

    int t = threadIdx.x;
    int w = t >> 6, lane = t & 63;       // w = 0..7
    int frow = lane & 15, quad = lane >> 4;
    int key = (frow >> 1) & 3;           // bank-swizzle key (period 2 rows)
    int rot = (quad ^ key) * 8;          // swizzled frag-read granule offset

    // ---------------- phase 1 ----------------
    int gsw = ((lane & 3) ^ ((lane >> 3) & 3)) * 8;
    const ushort* Xb = X + (((size_t)b) << 8) * (size_t)Kpad;
    const ushort* gB0 = Xb + (size_t)(32 * w +  0 + (lane >> 2)) * Kpad + gsw;
    const ushort* gB1 = Xb + (size_t)(32 * w + 16 + (lane >> 2)) * Kpad + gsw;
    const ushort* gA0 = Wt + (size_t)(f0 + 16 * w + (lane >> 2)) * Kpad + gsw;

    floatx4 acc[2][8];   // acc[i][j]: i = c-tile (X rows), j = f-tile (Wt rows)
    #pragma unroll
    for (int i = 0; i < 2; ++i)
        #pragma unroll
        for (int j = 0; j < 8; ++j) acc[i][j] = (floatx4)0.f;

    int nk1 = Kpad >> 5;                 // >= 4 for all layers

    // prologue: chunk 0 -> (As0,Bs0), chunk 1 -> (As1,Bs1); 3 DMAs/wave each
    {
        ushort* Bd = Bs0 + w * 1024;
        gl_lds16(gB0, Bd);  gl_lds16(gB1, Bd + 512);
        gl_lds16(gA0, As0 + w * 512);
        ushort* Bd1 = Bs1 + w * 1024;
        gl_lds16(gB0 + 32, Bd1);  gl_lds16(gB1 + 32, Bd1 + 512);
        gl_lds16(gA0 + 32, As1 + w * 512);
    }
    __builtin_amdgcn_sched_barrier(0);
    asm volatile("s_waitcnt vmcnt(3)" ::: "memory");   // chunk 0 resident
    __builtin_amdgcn_s_barrier();
    __builtin_amdgcn_sched_barrier(0);

    ushort *a0 = As0, *a1 = As1, *a2 = As2;   // a0 holds chunk ks
    ushort *b0p = Bs0, *b1p = Bs1, *b2p = Bs2; // b0p holds chunk ks

    for (int ks = 0; ks < nk1; ++ks) {
        // frag reads of chunk ks (swizzled granule = quad ^ key); compiler
        // inserts the lgkm waits before MFMA use -- no explicit drain needed
        const ushort* Ab = a0 + frow * 32 + rot;
        const ushort* Bb = b0p + (w * 32 + frow) * 32 + rot;
        short8 xf[2], wf[8];
        #pragma unroll
        for (int i = 0; i < 2; ++i)
            xf[i] = u4_frag(*(const uint4*)(Bb + i * 512));   // A operand: X rows
        #pragma unroll
        for (int j = 0; j < 8; ++j)
            wf[j] = u4_frag(*(const uint4*)(Ab + j * 512));   // B operand: Wt rows
        if (ks + 2 < nk1) {              // stage chunk ks+2 into 3rd buffers
            int off = (ks + 2) * 32;     // (disjoint from all current reads)
            ushort* Bd = b2p + w * 1024;
            gl_lds16(gB0 + off, Bd);  gl_lds16(gB1 + off, Bd + 512);
            gl_lds16(gA0 + off, a2 + w * 512);
        }
        __builtin_amdgcn_s_setprio(1);   // T5
        #pragma unroll
        for (int i = 0; i < 2; ++i)
            #pragma unroll
            for (int j = 0; j < 8; ++j)
                acc[i][j] = __builtin_amdgcn_mfma_f32_16x16x32_bf16(xf[i], wf[j], acc[i][j], 0, 0, 0);
        __builtin_amdgcn_s_setprio(0);
        __builtin_amdgcn_sched_barrier(0);
        if (ks + 2 < nk1)                 // wait chunk ks+1 (3 oldest); ks+2 in flight
            asm volatile("s_waitcnt vmcnt(3)" ::: "memory");
        else
            asm volatile("s_waitcnt vmcnt(0)" ::: "memory");
        __builtin_amdgcn_s_barrier();
        __builtin_amdgcn_sched_barrier(0);
        ushort* ta = a0; a0 = a1; a1 = a2; a2 = ta;     // rotate As (period 3)
        ushort* tb = b0p; b0p = b1p; b1p = b2p; b2p = tb; // rotate Bs (period 3)
    }

    // issue phase-2 ks=0 S loads NOW: overlap with the epilogue
    const ushort* Sp = Sg + (size_t)(w * 32 + frow) * 256 + quad * 8;
    uint4 ps[2];
    #pragma unroll
    for (int i = 0; i < 2; ++i) ps[i] = *(const uint4*)(Sp + i * 4096);

    // epilogue 1 -> Ys: c = w*32+i*16+quad*4+r (4 consecutive -> b64 write),
    // f = j*16+frow. chunk = w, gc = 2i+(quad>>1); granule position gc ^ key.
    #pragma unroll
    for (int j = 0; j < 8; ++j) {
        int f = j * 16 + frow;
        float bv = (f0 + f < Nfeat) ? bias[f0 + f] : 0.f;
        #pragma unroll
        for (int i = 0; i < 2; ++i) {
            int gc = 2 * i + (quad >> 1);
            int base = w * YCH + f * 32 + ((gc ^ key) * 8) + (quad & 1) * 4;
            uint lo = (uint)f2bf(acc[i][j][0] + bv) | ((uint)f2bf(acc[i][j][1] + bv) << 16);
            uint hi = (uint)f2bf(acc[i][j][2] + bv) | ((uint)f2bf(acc[i][j][3] + bv) << 16);
            *(uint2*)(&Ys[base]) = make_uint2(lo, hi);
        }
    }
    __syncthreads();

    // ---------------- phase 2 (no barriers, S double-buffered) ----------------
    #pragma unroll
    for (int i = 0; i < 2; ++i)
        #pragma unroll
        for (int j = 0; j < 8; ++j) acc[i][j] = (floatx4)0.f;

    for (int ks = 0; ks < 8; ++ks) {
        uint4 pn[2];
        if (ks < 7) {
            #pragma unroll
            for (int i = 0; i < 2; ++i)
                pn[i] = *(const uint4*)(Sp + i * 4096 + (ks + 1) * 32);
        }
        short8 bf[8];
        #pragma unroll
        for (int j = 0; j < 8; ++j)
            bf[j] = u4_frag(*(const uint4*)(&Ys[ks * YCH + (j * 16 + frow) * 32 + rot]));
        __builtin_amdgcn_s_setprio(1);   // T5
        #pragma unroll
        for (int i = 0; i < 2; ++i) {
            short8 af = u4_frag(ps[i]);
            #pragma unroll
            for (int j = 0; j < 8; ++j)
                acc[i][j] = __builtin_amdgcn_mfma_f32_16x16x32_bf16(af, bf[j], acc[i][j], 0, 0, 0);
        }
        __builtin_amdgcn_s_setprio(0);
        #pragma unroll
        for (int i = 0; i < 2; ++i) ps[i] = pn[i];
    }

    // epilogue 2: r = w*32+i*16+quad*4+reg, f = j*16+frow; guard f-tile pad
    #pragma unroll
    for (int i = 0; i < 2; ++i)
        #pragma unroll
        for (int r = 0; r < 4; ++r) {
            int rg = w * 32 + i * 16 + quad * 4 + r;
            ushort* Zr = Z + (size_t)((b << 8) + rg) * FsN + f0;
            #pragma unroll
            for (int j = 0; j < 8; ++j)
                if (f0 + j * 16 < FsN)
                    Zr[j * 16 + frow] = f2bf(fmaxf(acc[i][j][r], 0.f));
        }
}

// ---------------- L5 fused: gemm N=2 (+bias) -> spmm(F=2, dense Sd) + relu ----------------
// 512 threads: gemm K-split + spmm column-split (th halves), LDS combine.
__global__ __launch_bounds__(512) void l5_fused(const ushort* __restrict__ X,
                                                const float* __restrict__ Sd2,
                                                const float* __restrict__ Wd2,
                                                const float* __restrict__ bd2,
                                                float* __restrict__ out) {
    __shared__ float ysh[512];
    __shared__ float psum[1024];    // [2 halves][256 rows][2 feats]
    int b = blockIdx.x, t = threadIdx.x;
    int t0 = t & 255, th = t >> 8;
    // gemm partial: half th covers i in [25*th, 25*th+25) (k = 8i..8i+7)
    const uint4* Xr = (const uint4*)(X + ((size_t)((b << 8) + t0)) * 448);
    const float4* Wp = (const float4*)Wd2;
    float a0 = th == 0 ? bd2[0] : 0.f, a1 = th == 0 ? bd2[1] : 0.f;
    for (int ii = 0; ii < 25; ++ii) {
        int i = th * 25 + ii;
        uint4 p = Xr[i];
        uint pv[4] = {p.x, p.y, p.z, p.w};
        #pragma unroll
        for (int q = 0; q < 4; ++q) {
            float x0 = bf2f((ushort)(pv[q] & 0xffffu));
            float x1 = bf2f((ushort)(pv[q] >> 16));
            float4 w = Wp[i * 4 + q];
            a0 = fmaf(x0, w.x, a0); a1 = fmaf(x0, w.y, a1);
            a0 = fmaf(x1, w.z, a0); a1 = fmaf(x1, w.w, a1);
        }
    }
    psum[th * 512 + t0 * 2] = a0; psum[th * 512 + t0 * 2 + 1] = a1;
    __syncthreads();
    if (th == 0) {
        ysh[t0 * 2]     = psum[t0 * 2]     + psum[512 + t0 * 2];
        ysh[t0 * 2 + 1] = psum[t0 * 2 + 1] + psum[512 + t0 * 2 + 1];
    }
    __syncthreads();
    // partial spmm: row t0, half th covers columns [128*th, 128*th+128)
    float s0 = 0.f, s1 = 0.f;
    if (t0 < NN) {
        const float4* Sr = (const float4*)(Sd2 + (size_t)t0 * 256 + th * 128);
        #pragma unroll 8
        for (int c4 = 0; c4 < 32; ++c4) {
            float4 v = Sr[c4];
            const float2* yp = (const float2*)&ysh[th * 256 + c4 * 8];
            float2 y0 = yp[0], y1 = yp[1], y2 = yp[2], y3 = yp[3];
            s0 = fmaf(v.x, y0.x, s0); s1 = fmaf(v.x, y0.y, s1);
            s0 = fmaf(v.y, y1.x, s0); s1 = fmaf(v.y, y1.y, s1);
            s0 = fmaf(v.z, y2.x, s0); s1 = fmaf(v.z, y2.y, s1);
            s0 = fmaf(v.w, y3.x, s0); s1 = fmaf(v.w, y3.y, s1);
        }
    }
    psum[th * 512 + t0 * 2] = s0; psum[th * 512 + t0 * 2 + 1] = s1;
    __syncthreads();
    if (th == 0 && t0 < NN) {
        out[((size_t)b * NN + t0) * 2]     = fmaxf(psum[t0 * 2]     + psum[512 + t0 * 2],     0.f);
        out[((size_t)b * NN + t0) * 2 + 1] = fmaxf(psum[t0 * 2 + 1] + psum[512 + t0 * 2 + 1], 0.f);
    }
}

extern "C" void kernel_launch(void* const* d_in, const int* in_sizes, int n_in,
                              void* d_out, int out_size, void* d_ws, size_t ws_size,
                              hipStream_t stream) {
    const float* H = (const float*)d_in[0];
    const int*   g_rows[4] = {(const int*)d_in[1], (const int*)d_in[4], (const int*)d_in[7], (const int*)d_in[10]};
    const int*   g_cols[4] = {(const int*)d_in[2], (const int*)d_in[5], (const int*)d_in[8], (const int*)d_in[11]};
    const float* g_vals[4] = {(const float*)d_in[3], (const float*)d_in[6], (const float*)d_in[9], (const float*)d_in[12]};
    const float* W0  = (const float*)d_in[13]; const float* b0  = (const float*)d_in[14];
    const float* W1  = (const float*)d_in[15]; const float* b1  = (const float*)d_in[16];
    const float* W2  = (const float*)d_in[17]; const float* b2  = (const float*)d_in[18];
    const float* Wd0 = (const float*)d_in[19]; const float* bd0 = (const float*)d_in[20];
    const float* Wd1 = (const float*)d_in[21]; const float* bd1 = (const float*)d_in[22];
    const float* Wd2 = (const float*)d_in[23]; const float* bd2 = (const float*)d_in[24];
    float* out = (float*)d_out;

    const int nnz = in_sizes[1];
    const int B   = in_sizes[0] / (NN * 2);   // 256
    const int Mp  = B * 256;                  // 65536 (padded)

    // ---- workspace (ushort units) ----
    ushort* bufA = (ushort*)d_ws;                    // N-layout [Mp, <=448]
    ushort* bufB = bufA + (size_t)Mp * 448;          // N-layout [Mp, <=320]
    ushort* Wt1 = bufB + (size_t)Mp * 320;           // [384,416]
    ushort* Wt2 = Wt1 + 384 * 416;                   // [128,320]
    ushort* Wt3 = Wt2 + 128 * 320;                   // [384,128]
    ushort* Wt4 = Wt3 + 384 * 128;                   // [512,320]
    ushort* Sb  = Wt4 + 512 * 320;                   // 4 x [256,256] bf16
    float*  rs  = (float*)(Sb + 4 * 65536);          // 4*256
    float*  Sd  = rs + 4 * 256;                      // 4*65536
    const int ZN = 4 * 256 + 4 * 65536;

    // setup: 3 launches
    zero_k<<<(ZN + 255) / 256, 256, 0, stream>>>((int*)rs, ZN);
    edge_k<<<dim3((nnz + 255) / 256, 4), 256, 0, stream>>>(
        g_rows[0], g_cols[0], g_vals[0], g_rows[1], g_cols[1], g_vals[1],
        g_rows[2], g_cols[2], g_vals[2], g_rows[3], g_cols[3], g_vals[3],
        Sd, rs, nnz);
    conv_k<<<(675840 + 255) / 256, 256, 0, stream>>>(Sd, Sb, W1, Wt1, W2, Wt2, Wd0, Wt3, Wd1, Wt4);

    // L0: [2->400] g0, commuted spmm-first, fused.  H -> bufA[Mp,416]
    l0_fused<<<B, 512, 0, stream>>>(H, Sd + 0 * 65536, W0, b0, rs + 0, bufA);

    // L1: [400->300] g0.  bufA(K416) -> bufB(FsN 320), 3 x 128-f tiles
    fused_layer<<<B * 3, 512, 0, stream>>>(bufA, Wt1, Sb + 0 * 65536, b1, bufB, 416, 300, 320, 3);
    // L2: [300->100] g1.  bufB(K320) -> bufA(FsN 128), 1 x 128-f tile
    fused_layer<<<B * 1, 512, 0, stream>>>(bufB, Wt2, Sb + 1 * 65536, b2, bufA, 320, 100, 128, 1);
    // L3: [100->300] g3.  bufA(K128) -> bufB(FsN 320), 3 x 128-f tiles
    fused_layer<<<B * 3, 512, 0, stream>>>(bufA, Wt3, Sb + 3 * 65536, bd0, bufB, 128, 300, 320, 3);
    // L4: [300->400] g2.  bufB(K320) -> bufA(FsN 448), 4 x 128-f tiles
    fused_layer<<<B * 4, 512, 0, stream>>>(bufB, Wt4, Sb + 2 * 65536, bd1, bufA, 320, 400, 448, 4);

    // L5: [400->2] g2, fused.  bufA(stride 448, K=400) -> out[B*255,2]
    l5_fused<<<B, 512, 0, stream>>>(bufA, Sd + 2 * 65536, Wd2, bd2, out);
}